// Round 6
// baseline (498.466 us; speedup 1.0000x reference)
//
#include <hip/hip_runtime.h>
#include <hip/hip_bf16.h>

#define N_NODES 10000
#define N_EDGES 160000
#define HID 300
#define HIDP 304
#define KS 328                        // H-plane k-stride in shorts
#define RBM 80                        // partB rows/block (5 M-tiles); exact 1875
#define RBF 16                        // gather rows/block (1 M-tile) -> 625 blocks
#define PARTB_BLOCKS 1875             // 150000/80 exact
#define GEMMA_BLOCKS 125              // 10000/80 exact
#define FILL_BLOCKS 313               // ceil(160000/512)
#define PRE_BLOCKS (GEMMA_BLOCKS + FILL_BLOCKS)
#define FUSE_BLOCKS 625               // 10000/16 exact
#define MIX_BLOCKS 1099               // 157*7: period-7 interleave (3 partB : 4 gather)

typedef __attribute__((ext_vector_type(8))) short short8;
typedef __attribute__((ext_vector_type(4))) short s16x4;
typedef __attribute__((ext_vector_type(4))) float f32x4;

#define MFMA_B16(a, b, c) __builtin_amdgcn_mfma_f32_16x16x32_bf16(a, b, c, 0, 0, 0)

__device__ __forceinline__ short bf16r(float x) {
    unsigned u = __float_as_uint(x);
    return (short)((u + 0x7fffu + ((u >> 16) & 1u)) >> 16);
}
__device__ __forceinline__ float b2f(unsigned short u) {
    return __uint_as_float(((unsigned)u) << 16);
}
__device__ __forceinline__ void split1(float x, short& hi, short& lo) {
    short h = bf16r(x);
    float hf = __uint_as_float(((unsigned)(unsigned short)h) << 16);
    hi = h;
    lo = bf16r(x - hf);
}

// ---------------------------------------------------------------------------
// k_prep: weight pre-split (layout verified) + degree count.
// ---------------------------------------------------------------------------
__global__ void k_prep(const float* __restrict__ g0w, const float* __restrict__ gw,
                       short* __restrict__ wt0, short* __restrict__ wtl,
                       const int* __restrict__ col, int* __restrict__ cnt) {
    int idx = blockIdx.x * 256 + threadIdx.x;
    if (idx < N_EDGES) atomicAdd(&cnt[col[idx]], 1);
    if (idx < 1216) {
        int n16 = idx & 15, q = (idx >> 4) & 3, nt = idx >> 6;
        int n = nt * 16 + n16;
        short* hd = wt0 + (size_t)(nt * 8 + q) * 128 + n16 * 8;
        short* ld = wt0 + (size_t)(nt * 8 + 4 + q) * 128 + n16 * 8;
#pragma unroll
        for (int j = 0; j < 8; ++j) {
            int k = q * 8 + j;
            float f = (n < HID) ? g0w[k * HID + n] : 0.0f;
            short hi, lo;
            split1(f, hi, lo);
            hd[j] = hi;
            ld[j] = lo;
        }
    } else if (idx < 1216 + 48640) {
        int i = idx - 1216;
        int n16 = i & 15; i >>= 4;
        int q = i & 3; i >>= 2;
        int nt = i % 19; i /= 19;
        int chunk = i % 10;
        int l = i / 10;
        int n = nt * 16 + n16;
        int cnt_idx = chunk * 19 + nt;
        short* base = wtl + (size_t)l * 194560;
        short* hd = base + (size_t)(cnt_idx * 8 + q) * 128 + n16 * 8;
        short* ld = base + (size_t)(cnt_idx * 8 + 4 + q) * 128 + n16 * 8;
#pragma unroll
        for (int j = 0; j < 8; ++j) {
            int k = chunk * 32 + q * 8 + j;
            float f = (k < HID && n < HID) ? gw[((size_t)l * HID + k) * HID + n] : 0.0f;
            short hi, lo;
            split1(f, hi, lo);
            hd[j] = hi;
            ld[j] = lo;
        }
    }
}

// k_scan: 1024 threads, 10 iterations (verified)
__global__ __launch_bounds__(1024) void k_scan(
    const int* __restrict__ cnt, int* __restrict__ col_start,
    int* __restrict__ cursor, float* __restrict__ dinv,
    float* __restrict__ selfnorm) {
    __shared__ int wsum[16];
    int t = threadIdx.x;
    int lane = t & 63, w = t >> 6;
    int carry = 0;
    for (int base = 0; base < N_NODES; base += 1024) {
        int i = base + t;
        int v = (i < N_NODES) ? cnt[i] : 0;
        int s = v;
#pragma unroll
        for (int d = 1; d < 64; d <<= 1) {
            int n = __shfl_up(s, d, 64);
            if (lane >= d) s += n;
        }
        if (lane == 63) wsum[w] = s;
        __syncthreads();
        int woff = 0, total = 0;
#pragma unroll
        for (int k = 0; k < 16; ++k) {
            if (k < w) woff += wsum[k];
            total += wsum[k];
        }
        if (i < N_NODES) {
            int excl = carry + woff + s - v;
            col_start[i] = excl;
            cursor[i] = excl;
            float dd = (float)v + 1.0f;
            dinv[i] = rsqrtf(dd);
            selfnorm[i] = 1.0f / dd;
        }
        carry += total;
        __syncthreads();
    }
    if (t == 0) col_start[N_NODES] = carry;
}

// ---------------------------------------------------------------------------
// GCN core, single-buffered (R0-verified; partB path: 124/128 regs full).
// ---------------------------------------------------------------------------
template <int MT, int NTC>
__device__ __forceinline__ void kloop(const short* __restrict__ wp, int nch,
                                      const short* Hh, int nt0, int quad, int l16,
                                      f32x4 (&acc)[MT][NTC]) {
#pragma unroll
    for (int mt = 0; mt < MT; ++mt)
#pragma unroll
        for (int i = 0; i < NTC; ++i)
#pragma unroll
            for (int r = 0; r < 4; ++r) acc[mt][i][r] = 0.0f;
#pragma unroll 1
    for (int c = 0; c < nch; ++c) {
        const short* cb = wp + (size_t)(c * 19 + nt0) * 1024 + quad * 128 + l16 * 8;
        short8 ah[MT];
#pragma unroll
        for (int mt = 0; mt < MT; ++mt)
            ah[mt] = *(const short8*)&Hh[(mt * 16 + l16) * KS + c * 32 + quad * 8];
        short8 bb[NTC];
#pragma unroll
        for (int i = 0; i < NTC; ++i) bb[i] = *(const short8*)(cb + (size_t)i * 1024);
#pragma unroll
        for (int mt = 0; mt < MT; ++mt)
#pragma unroll
            for (int i = 0; i < NTC; ++i)
                acc[mt][i] = MFMA_B16(ah[mt], bb[i], acc[mt][i]);
#pragma unroll
        for (int i = 0; i < NTC; ++i) bb[i] = *(const short8*)(cb + (size_t)i * 1024 + 512);
#pragma unroll
        for (int mt = 0; mt < MT; ++mt)
#pragma unroll
            for (int i = 0; i < NTC; ++i)
                acc[mt][i] = MFMA_B16(ah[mt], bb[i], acc[mt][i]);
    }
}

// Software-pipelined kloop (gather-GEMM only, MT=1: ~50 spare VGPRs; R5-verified)
template <int MT, int NTC>
__device__ __forceinline__ void kloop_p(const short* __restrict__ wp, int nch,
                                        const short* Hh, int nt0, int quad, int l16,
                                        f32x4 (&acc)[MT][NTC]) {
#pragma unroll
    for (int mt = 0; mt < MT; ++mt)
#pragma unroll
        for (int i = 0; i < NTC; ++i)
#pragma unroll
            for (int r = 0; r < 4; ++r) acc[mt][i][r] = 0.0f;

    const short* a0 = Hh + l16 * KS + quad * 8;
    const short* w0 = wp + (size_t)nt0 * 1024 + (size_t)(quad * 128 + l16 * 8);

    short8 ah[MT], an[MT], b1[NTC], b1n[NTC], b2[NTC];
#pragma unroll
    for (int mt = 0; mt < MT; ++mt) ah[mt] = *(const short8*)(a0 + mt * 16 * KS);
#pragma unroll
    for (int i = 0; i < NTC; ++i) b1[i] = *(const short8*)(w0 + (size_t)i * 1024);

#pragma unroll 1
    for (int c = 0; c < nch - 1; ++c) {
        const short* wc = w0 + (size_t)c * 19456;
        const short* wn = wc + 19456;
        const short* apn = a0 + (c + 1) * 32;
#pragma unroll
        for (int i = 0; i < NTC; ++i) b2[i] = *(const short8*)(wc + (size_t)i * 1024 + 512);
#pragma unroll
        for (int mt = 0; mt < MT; ++mt) an[mt] = *(const short8*)(apn + mt * 16 * KS);
#pragma unroll
        for (int i = 0; i < NTC; ++i) b1n[i] = *(const short8*)(wn + (size_t)i * 1024);
#pragma unroll
        for (int mt = 0; mt < MT; ++mt)
#pragma unroll
            for (int i = 0; i < NTC; ++i) acc[mt][i] = MFMA_B16(ah[mt], b1[i], acc[mt][i]);
#pragma unroll
        for (int mt = 0; mt < MT; ++mt)
#pragma unroll
            for (int i = 0; i < NTC; ++i) acc[mt][i] = MFMA_B16(ah[mt], b2[i], acc[mt][i]);
#pragma unroll
        for (int mt = 0; mt < MT; ++mt) ah[mt] = an[mt];
#pragma unroll
        for (int i = 0; i < NTC; ++i) b1[i] = b1n[i];
    }
    {
        const short* wc = w0 + (size_t)(nch - 1) * 19456;
#pragma unroll
        for (int i = 0; i < NTC; ++i) b2[i] = *(const short8*)(wc + (size_t)i * 1024 + 512);
#pragma unroll
        for (int mt = 0; mt < MT; ++mt)
#pragma unroll
            for (int i = 0; i < NTC; ++i) acc[mt][i] = MFMA_B16(ah[mt], b1[i], acc[mt][i]);
#pragma unroll
        for (int mt = 0; mt < MT; ++mt)
#pragma unroll
            for (int i = 0; i < NTC; ++i) acc[mt][i] = MFMA_B16(ah[mt], b2[i], acc[mt][i]);
    }
}

template <int MT, int NTC>
__device__ __forceinline__ void gcn_epilogue(const float* __restrict__ bias,
                                             int nt0, int quad, int l16,
                                             f32x4 (&acc)[MT][NTC], short* Hh) {
#pragma unroll
    for (int i = 0; i < NTC; ++i) {
        int c = (nt0 + i) * 16 + l16;
        float b = (c < HID) ? bias[c] : 0.0f;
#pragma unroll
        for (int mt = 0; mt < MT; ++mt)
#pragma unroll
            for (int r = 0; r < 4; ++r) {
                float v = fmaxf(acc[mt][i][r] + b, 0.0f);
                Hh[(mt * 16 + quad * 4 + r) * KS + c] = bf16r(v);
            }
    }
}

template <int MT, int NTC>
__device__ __forceinline__ void gcn_final(const float* __restrict__ bias,
                                          int nt0, int quad, int l16,
                                          f32x4 (&acc)[MT][NTC],
                                          float* __restrict__ gout) {
#pragma unroll
    for (int i = 0; i < NTC; ++i) {
        int c = (nt0 + i) * 16 + l16;
        float b = (c < HID) ? bias[c] : 0.0f;
        float s = 0.0f;
#pragma unroll
        for (int mt = 0; mt < MT; ++mt)
#pragma unroll
            for (int r = 0; r < 4; ++r) s += fmaxf(acc[mt][i][r] + b, 0.0f);
        s += __shfl_xor(s, 16, 64);
        s += __shfl_xor(s, 32, 64);
        if (quad == 0) gout[c] = (c < HID) ? s : 0.0f;
    }
}

template <int MT, int NTC>
__device__ __forceinline__ void gemm_out(int base, int nt0, int quad, int l16,
                                         f32x4 (&acc)[MT][NTC],
                                         unsigned short* __restrict__ HW) {
#pragma unroll
    for (int i = 0; i < NTC; ++i) {
        int c = (nt0 + i) * 16 + l16;
#pragma unroll
        for (int mt = 0; mt < MT; ++mt)
#pragma unroll
            for (int r = 0; r < 4; ++r) {
                int gm = base + mt * 16 + quad * 4 + r;
                if (gm < N_NODES)
                    HW[(size_t)gm * HIDP + c] = (unsigned short)bf16r(acc[mt][i][r]);
            }
    }
}

// partB 5-layer fused unit on 80 rows (body shared by k_mix) --------------
__device__ __forceinline__ void partB_unit(
    int pb, int t, int w, int lane, int l16, int quad, int nt0,
    const float* __restrict__ edge_attr, const float* __restrict__ edge_w,
    const float* __restrict__ edge_b, const short* __restrict__ wt0,
    const short* __restrict__ wtl, const float* __restrict__ gcn0_b,
    const float* __restrict__ gcn_b, float* __restrict__ gpartB, short* Hh) {
    int base = N_NODES + pb * RBM;
    for (int i = t; i < RBM * 8; i += 512) {
        int r = i >> 3, c4 = (i & 7) * 4;
        const float* ar = edge_attr + (size_t)(base + r) * 3;
        float a0 = ar[0], a1 = ar[1], a2 = ar[2];
#pragma unroll
        for (int j = 0; j < 4; ++j) {
            int cc = c4 + j;
            float v = edge_b[cc];
            v = fmaf(a0, edge_w[cc], v);
            v = fmaf(a1, edge_w[32 + cc], v);
            v = fmaf(a2, edge_w[64 + cc], v);
            Hh[r * KS + cc] = bf16r(v);
        }
    }
    for (int i = t; i < RBM * 24; i += 512) {
        int r = i / 24, k = 304 + i % 24;
        Hh[r * KS + k] = 0;
    }
    __syncthreads();

    float* gout = gpartB + (size_t)pb * HIDP;
    if (w < 3) {
        f32x4 acc[5][3];
        kloop<5, 3>(wt0, 1, Hh, nt0, quad, l16, acc);
        __syncthreads();
        gcn_epilogue<5, 3>(gcn0_b, nt0, quad, l16, acc, Hh);
        __syncthreads();
        for (int l = 0; l < 4; ++l) {
            kloop<5, 3>(wtl + (size_t)l * 194560, 10, Hh, nt0, quad, l16, acc);
            __syncthreads();
            if (l < 3) {
                gcn_epilogue<5, 3>(gcn_b + l * HID, nt0, quad, l16, acc, Hh);
                __syncthreads();
            } else {
                gcn_final<5, 3>(gcn_b + l * HID, nt0, quad, l16, acc, gout);
            }
        }
    } else {
        f32x4 acc[5][2];
        kloop<5, 2>(wt0, 1, Hh, nt0, quad, l16, acc);
        __syncthreads();
        gcn_epilogue<5, 2>(gcn0_b, nt0, quad, l16, acc, Hh);
        __syncthreads();
        for (int l = 0; l < 4; ++l) {
            kloop<5, 2>(wtl + (size_t)l * 194560, 10, Hh, nt0, quad, l16, acc);
            __syncthreads();
            if (l < 3) {
                gcn_epilogue<5, 2>(gcn_b + l * HID, nt0, quad, l16, acc, Hh);
                __syncthreads();
            } else {
                gcn_final<5, 2>(gcn_b + l * HID, nt0, quad, l16, acc, gout);
            }
        }
    }
}

// ---------------------------------------------------------------------------
// k_pre: Part-A layer-0 GEMM (125) + CSR fill (313). Must complete before the
// first mixed launch (hw0 + edge_pack dependencies via launch boundary).
// ---------------------------------------------------------------------------
__global__ __launch_bounds__(512, 4) void k_pre(
    const float* __restrict__ edge_attr,
    const float* __restrict__ edge_w,
    const float* __restrict__ edge_b,
    const short* __restrict__ wt0,
    unsigned short* __restrict__ hw0,
    const int* __restrict__ row,
    const int* __restrict__ col,
    int* __restrict__ cursor,
    const float* __restrict__ dinv,
    int2* __restrict__ edge_pack) {
    __shared__ short Hh[RBM * KS];
    int bid = blockIdx.x, t = threadIdx.x;
    int lane = t & 63, w = t >> 6;
    int l16 = lane & 15, quad = lane >> 4;
    int nt0 = (w < 3) ? w * 3 : 9 + (w - 3) * 2;

    if (bid < GEMMA_BLOCKS) {
        int base = bid * RBM;
        for (int i = t; i < RBM * 8; i += 512) {
            int r = i >> 3, c4 = (i & 7) * 4;
            const float* ar = edge_attr + (size_t)(base + r) * 3;
            float a0 = ar[0], a1 = ar[1], a2 = ar[2];
#pragma unroll
            for (int j = 0; j < 4; ++j) {
                int cc = c4 + j;
                float v = edge_b[cc];
                v = fmaf(a0, edge_w[cc], v);
                v = fmaf(a1, edge_w[32 + cc], v);
                v = fmaf(a2, edge_w[64 + cc], v);
                Hh[r * KS + cc] = bf16r(v);
            }
        }
        for (int i = t; i < RBM * 24; i += 512) {
            int r = i / 24, k = 304 + i % 24;
            Hh[r * KS + k] = 0;
        }
        __syncthreads();
        if (w < 3) {
            f32x4 acc[5][3];
            kloop<5, 3>(wt0, 1, Hh, nt0, quad, l16, acc);
            gemm_out<5, 3>(base, nt0, quad, l16, acc, hw0);
        } else {
            f32x4 acc[5][2];
            kloop<5, 2>(wt0, 1, Hh, nt0, quad, l16, acc);
            gemm_out<5, 2>(base, nt0, quad, l16, acc, hw0);
        }
    } else {
        int e = (bid - GEMMA_BLOCKS) * 512 + t;
        if (e < N_EDGES) {
            int c = col[e], r = row[e];
            int p = atomicAdd(&cursor[c], 1);
            edge_pack[p] = make_int2(r, __float_as_int(dinv[r] * dinv[c]));
        }
    }
}

// ---------------------------------------------------------------------------
// agg primitives (scalar u16 gather — verified form; cache-line requests are
// the cost unit, do NOT widen).
// ---------------------------------------------------------------------------
__device__ __forceinline__ void agg_edge4(int i, int lane,
                                          const unsigned short* __restrict__ hw_in,
                                          const int2* __restrict__ ep,
                                          float (&v)[5]) {
    int2 e0 = ep[i], e1 = ep[i + 1], e2 = ep[i + 2], e3 = ep[i + 3];
    const unsigned short* h0 = hw_in + (size_t)e0.x * HIDP;
    const unsigned short* h1 = hw_in + (size_t)e1.x * HIDP;
    const unsigned short* h2 = hw_in + (size_t)e2.x * HIDP;
    const unsigned short* h3 = hw_in + (size_t)e3.x * HIDP;
    float n0 = __int_as_float(e0.y), n1 = __int_as_float(e1.y);
    float n2 = __int_as_float(e2.y), n3 = __int_as_float(e3.y);
#pragma unroll
    for (int jj = 0; jj < 5; ++jj) {
        int cc = lane + 64 * jj;
        if (cc < HIDP) {
            float s = v[jj];
            s = fmaf(n0, b2f(h0[cc]), s);
            s = fmaf(n1, b2f(h1[cc]), s);
            s = fmaf(n2, b2f(h2[cc]), s);
            s = fmaf(n3, b2f(h3[cc]), s);
            v[jj] = s;
        }
    }
}

__device__ __forceinline__ void agg_pair(int c0, int c1, int lane,
                                         const unsigned short* __restrict__ hw_in,
                                         const int* __restrict__ col_start,
                                         const int2* __restrict__ ep,
                                         float (&v0)[5], float (&v1)[5]) {
#pragma unroll
    for (int jj = 0; jj < 5; ++jj) { v0[jj] = 0.0f; v1[jj] = 0.0f; }
    int i0 = col_start[c0], e0 = col_start[c0 + 1];
    int i1 = col_start[c1], e1 = col_start[c1 + 1];
#pragma unroll 1
    while (i0 + 4 <= e0 && i1 + 4 <= e1) {
        int2 a0 = ep[i0], a1 = ep[i0 + 1], a2 = ep[i0 + 2], a3 = ep[i0 + 3];
        int2 b0 = ep[i1], b1 = ep[i1 + 1], b2 = ep[i1 + 2], b3 = ep[i1 + 3];
        const unsigned short* pa0 = hw_in + (size_t)a0.x * HIDP;
        const unsigned short* pa1 = hw_in + (size_t)a1.x * HIDP;
        const unsigned short* pa2 = hw_in + (size_t)a2.x * HIDP;
        const unsigned short* pa3 = hw_in + (size_t)a3.x * HIDP;
        const unsigned short* pb0 = hw_in + (size_t)b0.x * HIDP;
        const unsigned short* pb1 = hw_in + (size_t)b1.x * HIDP;
        const unsigned short* pb2 = hw_in + (size_t)b2.x * HIDP;
        const unsigned short* pb3 = hw_in + (size_t)b3.x * HIDP;
        float na0 = __int_as_float(a0.y), na1 = __int_as_float(a1.y);
        float na2 = __int_as_float(a2.y), na3 = __int_as_float(a3.y);
        float nb0 = __int_as_float(b0.y), nb1 = __int_as_float(b1.y);
        float nb2 = __int_as_float(b2.y), nb3 = __int_as_float(b3.y);
#pragma unroll
        for (int jj = 0; jj < 5; ++jj) {
            int cc = lane + 64 * jj;
            if (cc < HIDP) {
                float s = v0[jj];
                s = fmaf(na0, b2f(pa0[cc]), s);
                s = fmaf(na1, b2f(pa1[cc]), s);
                s = fmaf(na2, b2f(pa2[cc]), s);
                s = fmaf(na3, b2f(pa3[cc]), s);
                v0[jj] = s;
                float u = v1[jj];
                u = fmaf(nb0, b2f(pb0[cc]), u);
                u = fmaf(nb1, b2f(pb1[cc]), u);
                u = fmaf(nb2, b2f(pb2[cc]), u);
                u = fmaf(nb3, b2f(pb3[cc]), u);
                v1[jj] = u;
            }
        }
        i0 += 4; i1 += 4;
    }
#pragma unroll 1
    for (; i0 + 4 <= e0; i0 += 4) agg_edge4(i0, lane, hw_in, ep, v0);
#pragma unroll 1
    for (; i0 < e0; ++i0) {
        int2 q = ep[i0];
        const unsigned short* h = hw_in + (size_t)q.x * HIDP;
        float n = __int_as_float(q.y);
#pragma unroll
        for (int jj = 0; jj < 5; ++jj) {
            int cc = lane + 64 * jj;
            if (cc < HIDP) v0[jj] = fmaf(n, b2f(h[cc]), v0[jj]);
        }
    }
#pragma unroll 1
    for (; i1 + 4 <= e1; i1 += 4) agg_edge4(i1, lane, hw_in, ep, v1);
#pragma unroll 1
    for (; i1 < e1; ++i1) {
        int2 q = ep[i1];
        const unsigned short* h = hw_in + (size_t)q.x * HIDP;
        float n = __int_as_float(q.y);
#pragma unroll
        for (int jj = 0; jj < 5; ++jj) {
            int cc = lane + 64 * jj;
            if (cc < HIDP) v1[jj] = fmaf(n, b2f(h[cc]), v1[jj]);
        }
    }
}

// ---------------------------------------------------------------------------
// k_mix: one Part-A layer (gather 625 blocks) OVERLAPPED with a slice of the
// independent partB units (pcount blocks). Period-7 interleave (3 partB :
// 4 gather) so consecutive bids — round-robin across XCDs/CUs — give per-CU
// type mixing: gather waves (VMEM-bound) and partB waves (MFMA-bound) use
// complementary pipes (m114: co-schedule ~= max, not sum).
// ---------------------------------------------------------------------------
__global__ __launch_bounds__(512, 4) void k_mix(
    const unsigned short* __restrict__ hw_in,
    const int* __restrict__ col_start,
    const int2* __restrict__ edge_pack,
    const float* __restrict__ selfnorm,
    const float* __restrict__ bias,
    const short* __restrict__ wt,
    unsigned short* __restrict__ hw_out,
    const float* __restrict__ edge_attr,
    const float* __restrict__ edge_w,
    const float* __restrict__ edge_b,
    const short* __restrict__ wt0,
    const short* __restrict__ wtl,
    const float* __restrict__ gcn0_b,
    const float* __restrict__ gcn_b,
    float* __restrict__ gpartB,
    int pbase, int pcount) {
    __shared__ short Hh[RBM * KS];   // 52480 B (partB needs full; gather uses 16 rows)
    int bid = blockIdx.x, t = threadIdx.x;
    int lane = t & 63, w = t >> 6;
    int l16 = lane & 15, quad = lane >> 4;
    int nt0 = (w < 3) ? w * 3 : 9 + (w - 3) * 2;

    int kk = bid / 7, r7 = bid % 7;
    if (r7 < 3) {
        // ---------------- partB unit ----------------
        int pidx = kk * 3 + r7;
        if (pidx >= pcount) return;
        partB_unit(pbase + pidx, t, w, lane, l16, quad, nt0,
                   edge_attr, edge_w, edge_b, wt0, wtl, gcn0_b, gcn_b, gpartB, Hh);
    } else {
        // ---------------- gather + GEMM (one Part-A layer, 16 rows) --------
        int gidx = kk * 4 + (r7 - 3);
        if (gidx >= FUSE_BLOCKS) return;
        int base = gidx * RBF;
        {
            int c0 = base + w * 2, c1 = c0 + 1;   // 625*16 == 10000: always valid
            float v0[5], v1[5];
            agg_pair(c0, c1, lane, hw_in, col_start, edge_pack, v0, v1);
            float sn0 = selfnorm[c0], sn1 = selfnorm[c1];
            const unsigned short* sp0 = hw_in + (size_t)c0 * HIDP;
            const unsigned short* sp1 = hw_in + (size_t)c1 * HIDP;
            int r0 = w * 2;
#pragma unroll
            for (int jj = 0; jj < 5; ++jj) {
                int cc = lane + 64 * jj;
                if (cc < HIDP) {
                    float b = (cc < HID) ? bias[cc] : 0.0f;
                    float h0 = v0[jj] + sn0 * b2f(sp0[cc]) + b;
                    float h1 = v1[jj] + sn1 * b2f(sp1[cc]) + b;
                    Hh[r0 * KS + cc] = bf16r(fmaxf(h0, 0.0f));
                    Hh[(r0 + 1) * KS + cc] = bf16r(fmaxf(h1, 0.0f));
                }
            }
        }
        for (int i = t; i < RBF * 6; i += 512) {
            int r = i / 6, k = 304 + (i % 6) * 4;
            *(s16x4*)&Hh[r * KS + k] = (s16x4)0;
        }
        __syncthreads();

        if (w < 3) {
            f32x4 acc[1][3];
            kloop_p<1, 3>(wt, 10, Hh, nt0, quad, l16, acc);
            gemm_out<1, 3>(base, nt0, quad, l16, acc, hw_out);
        } else {
            f32x4 acc[1][2];
            kloop_p<1, 2>(wt, 10, Hh, nt0, quad, l16, acc);
            gemm_out<1, 2>(base, nt0, quad, l16, acc, hw_out);
        }
    }
}

// ---------------------------------------------------------------------------
// k_last: final Part-A agg + colsum into g_sum, with gpartB fold absorbed
// (waves 0..2 each add one gpartB row; 625*3 == 1875 exact). Pure (no partB
// blocks here — they'd race the fold).
// ---------------------------------------------------------------------------
__global__ __launch_bounds__(512) void k_last(
    const unsigned short* __restrict__ hw_in,
    const int* __restrict__ col_start,
    const int2* __restrict__ edge_pack,
    const float* __restrict__ selfnorm,
    const float* __restrict__ bias,
    const float* __restrict__ gpartB,
    float* __restrict__ g_sum) {
    __shared__ float red[8 * 320];
    int t = threadIdx.x;
    int lane = t & 63, w = t >> 6;
    int base = blockIdx.x * RBF;

    float s[5] = {0.0f, 0.0f, 0.0f, 0.0f, 0.0f};
    {
        int c0 = base + w * 2, c1 = c0 + 1;    // always valid
        float v0[5], v1[5];
        agg_pair(c0, c1, lane, hw_in, col_start, edge_pack, v0, v1);
        float sn0 = selfnorm[c0], sn1 = selfnorm[c1];
        const unsigned short* sp0 = hw_in + (size_t)c0 * HIDP;
        const unsigned short* sp1 = hw_in + (size_t)c1 * HIDP;
#pragma unroll
        for (int jj = 0; jj < 5; ++jj) {
            int cc = lane + 64 * jj;
            if (cc < HID) {
                float b = bias[cc];
                s[jj] += fmaxf(v0[jj] + sn0 * b2f(sp0[cc]) + b, 0.0f);
                s[jj] += fmaxf(v1[jj] + sn1 * b2f(sp1[cc]) + b, 0.0f);
            }
        }
    }
    if (w < 3) {
        int rr = blockIdx.x * 3 + w;
        if (rr < PARTB_BLOCKS) {
#pragma unroll
            for (int jj = 0; jj < 5; ++jj) {
                int cc = lane + 64 * jj;
                if (cc < HID) s[jj] += gpartB[(size_t)rr * HIDP + cc];
            }
        }
    }
#pragma unroll
    for (int jj = 0; jj < 5; ++jj) red[w * 320 + lane + 64 * jj] = s[jj];
    __syncthreads();
    if (w == 0) {
#pragma unroll
        for (int jj = 0; jj < 5; ++jj) {
            int cc = lane + 64 * jj;
            if (cc < HID) {
                float tot = 0.0f;
#pragma unroll
                for (int g = 0; g < 8; ++g) tot += red[g * 320 + cc];
                atomicAdd(&g_sum[cc], tot);
            }
        }
    }
}

__global__ void k_head(const float* __restrict__ g_sum,
                       const float* __restrict__ lin1_w, const float* __restrict__ lin1_b,
                       const float* __restrict__ lin2_w, const float* __restrict__ lin2_b,
                       float* __restrict__ out) {
    __shared__ float g2[32];
    int t = threadIdx.x;
    const float inv = 1.0f / (float)N_EDGES;
    if (t < 32) {
        float a = lin1_b[t];
        for (int d = 0; d < HID; ++d) a = fmaf(g_sum[d] * inv, lin1_w[d * 32 + t], a);
        g2[t] = fmaxf(a, 0.0f);
    }
    __syncthreads();
    if (t < 2) {
        float p = lin2_b[t];
        for (int j = 0; j < 32; ++j) p = fmaf(g2[j], lin2_w[j * 2 + t], p);
        out[t] = p;
    }
}

// ---------------------------------------------------------------------------

extern "C" void kernel_launch(void* const* d_in, const int* in_sizes, int n_in,
                              void* d_out, int out_size, void* d_ws, size_t ws_size,
                              hipStream_t stream) {
    (void)in_sizes; (void)n_in; (void)out_size; (void)ws_size;
    const int* edge_index = (const int*)d_in[1];
    const float* edge_attr = (const float*)d_in[2];
    const float* edge_w = (const float*)d_in[6];
    const float* edge_b = (const float*)d_in[7];
    const float* gcn0_w = (const float*)d_in[8];
    const float* gcn0_b = (const float*)d_in[9];
    const float* gcn_w = (const float*)d_in[10];
    const float* gcn_b = (const float*)d_in[11];
    const float* lin1_w = (const float*)d_in[12];
    const float* lin1_b = (const float*)d_in[13];
    const float* lin2_w = (const float*)d_in[14];
    const float* lin2_b = (const float*)d_in[15];

    char* ws = (char*)d_ws;
    size_t off = 0;
    auto alloc = [&](size_t bytes) {
        void* p = ws + off;
        off = (off + bytes + 255) & ~(size_t)255;
        return p;
    };
    unsigned short* hwA = (unsigned short*)alloc((size_t)N_NODES * HIDP * 2);
    unsigned short* hwB = (unsigned short*)alloc((size_t)N_NODES * HIDP * 2);
    int2* edge_pack = (int2*)alloc((size_t)N_EDGES * 8);
    int* cnt = (int*)alloc((size_t)N_NODES * 4);
    int* col_start = (int*)alloc((size_t)(N_NODES + 1) * 4);
    int* cursor = (int*)alloc((size_t)N_NODES * 4);
    float* dinv = (float*)alloc((size_t)N_NODES * 4);
    float* selfnorm = (float*)alloc((size_t)N_NODES * 4);
    float* g_sum = (float*)alloc((size_t)HIDP * 4);
    short* wt0 = (short*)alloc((size_t)38912);
    short* wtl = (short*)alloc((size_t)4 * 389120);
    float* gpartB = (float*)alloc((size_t)PARTB_BLOCKS * HIDP * 4);

    const int* row = edge_index;
    const int* col = edge_index + N_EDGES;

    hipMemsetAsync(cnt, 0, N_NODES * 4, stream);
    hipMemsetAsync(g_sum, 0, HIDP * 4, stream);

    k_prep<<<(N_EDGES + 255) / 256, 256, 0, stream>>>(gcn0_w, gcn_w, wt0, wtl, col, cnt);
    k_scan<<<1, 1024, 0, stream>>>(cnt, col_start, cursor, dinv, selfnorm);

    // k_pre: Part-A L0 GEMM + CSR fill (everything the fuse chain depends on)
    k_pre<<<PRE_BLOCKS, 512, 0, stream>>>(edge_attr, edge_w, edge_b, wt0, hwA,
                                          row, col, cursor, dinv, edge_pack);

    // Part A layers 1..4 overlapped with partB slices (469+469+469+468=1875)
    k_mix<<<MIX_BLOCKS, 512, 0, stream>>>(hwA, col_start, edge_pack, selfnorm,
                                          gcn0_b, wtl + (size_t)0 * 194560, hwB,
                                          edge_attr, edge_w, edge_b, wt0, wtl,
                                          gcn0_b, gcn_b, gpartB, 0, 469);
    k_mix<<<MIX_BLOCKS, 512, 0, stream>>>(hwB, col_start, edge_pack, selfnorm,
                                          gcn_b + 0 * HID, wtl + (size_t)1 * 194560, hwA,
                                          edge_attr, edge_w, edge_b, wt0, wtl,
                                          gcn0_b, gcn_b, gpartB, 469, 469);
    k_mix<<<MIX_BLOCKS, 512, 0, stream>>>(hwA, col_start, edge_pack, selfnorm,
                                          gcn_b + 1 * HID, wtl + (size_t)2 * 194560, hwB,
                                          edge_attr, edge_w, edge_b, wt0, wtl,
                                          gcn0_b, gcn_b, gpartB, 938, 469);
    k_mix<<<MIX_BLOCKS, 512, 0, stream>>>(hwB, col_start, edge_pack, selfnorm,
                                          gcn_b + 2 * HID, wtl + (size_t)3 * 194560, hwA,
                                          edge_attr, edge_w, edge_b, wt0, wtl,
                                          gcn0_b, gcn_b, gpartB, 1407, 468);
    // final agg + colsum + partB fold, then head
    k_last<<<FUSE_BLOCKS, 512, 0, stream>>>(hwA, col_start, edge_pack, selfnorm,
                                            gcn_b + 3 * HID, gpartB, g_sum);
    k_head<<<1, 64, 0, stream>>>(g_sum, lin1_w, lin1_b, lin2_w, lin2_b, (float*)d_out);
}

// Round 7
// 454.830 us; speedup vs baseline: 1.0959x; 1.0959x over previous
//
#include <hip/hip_runtime.h>
#include <hip/hip_bf16.h>

#define N_NODES 10000
#define N_EDGES 160000
#define HID 300
#define HIDP 304
#define KS 328                        // H-plane k-stride in shorts
#define RBM 80                        // mega rows/block (5 M-tiles); exact 1875
#define RBF 16                        // fuse rows/block (1 M-tile) -> 625 blocks
#define PARTB_BLOCKS 1875             // 150000/80 exact
#define GEMMA_BLOCKS 125              // 10000/80 exact
#define FILL_BLOCKS 313               // ceil(160000/512)
#define MEGA_BLOCKS (PARTB_BLOCKS + GEMMA_BLOCKS + FILL_BLOCKS)
#define FUSE_BLOCKS 625               // 10000/16 exact

typedef __attribute__((ext_vector_type(8))) short short8;
typedef __attribute__((ext_vector_type(4))) short s16x4;
typedef __attribute__((ext_vector_type(4))) float f32x4;

#define MFMA_B16(a, b, c) __builtin_amdgcn_mfma_f32_16x16x32_bf16(a, b, c, 0, 0, 0)

__device__ __forceinline__ short bf16r(float x) {
    unsigned u = __float_as_uint(x);
    return (short)((u + 0x7fffu + ((u >> 16) & 1u)) >> 16);
}
__device__ __forceinline__ float b2f(unsigned short u) {
    return __uint_as_float(((unsigned)u) << 16);
}
__device__ __forceinline__ void split1(float x, short& hi, short& lo) {
    short h = bf16r(x);
    float hf = __uint_as_float(((unsigned)(unsigned short)h) << 16);
    hi = h;
    lo = bf16r(x - hf);
}

// ---------------------------------------------------------------------------
// k_prep: weight pre-split (layout verified) + degree count.
// ---------------------------------------------------------------------------
__global__ void k_prep(const float* __restrict__ g0w, const float* __restrict__ gw,
                       short* __restrict__ wt0, short* __restrict__ wtl,
                       const int* __restrict__ col, int* __restrict__ cnt) {
    int idx = blockIdx.x * 256 + threadIdx.x;
    if (idx < N_EDGES) atomicAdd(&cnt[col[idx]], 1);
    if (idx < 1216) {
        int n16 = idx & 15, q = (idx >> 4) & 3, nt = idx >> 6;
        int n = nt * 16 + n16;
        short* hd = wt0 + (size_t)(nt * 8 + q) * 128 + n16 * 8;
        short* ld = wt0 + (size_t)(nt * 8 + 4 + q) * 128 + n16 * 8;
#pragma unroll
        for (int j = 0; j < 8; ++j) {
            int k = q * 8 + j;
            float f = (n < HID) ? g0w[k * HID + n] : 0.0f;
            short hi, lo;
            split1(f, hi, lo);
            hd[j] = hi;
            ld[j] = lo;
        }
    } else if (idx < 1216 + 48640) {
        int i = idx - 1216;
        int n16 = i & 15; i >>= 4;
        int q = i & 3; i >>= 2;
        int nt = i % 19; i /= 19;
        int chunk = i % 10;
        int l = i / 10;
        int n = nt * 16 + n16;
        int cnt_idx = chunk * 19 + nt;
        short* base = wtl + (size_t)l * 194560;
        short* hd = base + (size_t)(cnt_idx * 8 + q) * 128 + n16 * 8;
        short* ld = base + (size_t)(cnt_idx * 8 + 4 + q) * 128 + n16 * 8;
#pragma unroll
        for (int j = 0; j < 8; ++j) {
            int k = chunk * 32 + q * 8 + j;
            float f = (k < HID && n < HID) ? gw[((size_t)l * HID + k) * HID + n] : 0.0f;
            short hi, lo;
            split1(f, hi, lo);
            hd[j] = hi;
            ld[j] = lo;
        }
    }
}

// ---------------------------------------------------------------------------
// k_scan: one-pass blocked scan. Thread t owns nodes [t*10, t*10+10)
// (1024*10 = 10240 >= 10000): serial local prefix, one wave+LDS scan of
// per-thread totals, redistribute. 1 barrier instead of 20 (old version ran
// 10 serial scan iterations on a single CU — pure critical-path time).
// Integer scan -> outputs bit-identical to the old version.
// ---------------------------------------------------------------------------
__global__ __launch_bounds__(1024) void k_scan(
    const int* __restrict__ cnt, int* __restrict__ col_start,
    int* __restrict__ cursor, float* __restrict__ dinv,
    float* __restrict__ selfnorm) {
    __shared__ int wsum[16];
    int t = threadIdx.x;
    int lane = t & 63, w = t >> 6;
    int base = t * 10;
    int v[10];
    int tot = 0;
#pragma unroll
    for (int j = 0; j < 10; ++j) {
        int i = base + j;
        v[j] = (i < N_NODES) ? cnt[i] : 0;
        tot += v[j];
    }
    int s = tot;
#pragma unroll
    for (int d = 1; d < 64; d <<= 1) {
        int n = __shfl_up(s, d, 64);
        if (lane >= d) s += n;
    }
    if (lane == 63) wsum[w] = s;
    __syncthreads();
    int woff = 0;
#pragma unroll
    for (int k = 0; k < 16; ++k)
        if (k < w) woff += wsum[k];
    int excl = woff + s - tot;    // exclusive prefix at this thread's first node
#pragma unroll
    for (int j = 0; j < 10; ++j) {
        int i = base + j;
        if (i < N_NODES) {
            col_start[i] = excl;
            cursor[i] = excl;
            float dd = (float)v[j] + 1.0f;
            dinv[i] = rsqrtf(dd);
            selfnorm[i] = 1.0f / dd;
        }
        excl += v[j];
    }
    if (t == 1023) col_start[N_NODES] = excl;   // == grand total
}

// ---------------------------------------------------------------------------
// GCN core, single-buffered (R0-verified — k_mega: 124/128 regs full,
// R1/R2 lesson: no pipelining headroom at MT=5).
// ---------------------------------------------------------------------------
template <int MT, int NTC>
__device__ __forceinline__ void kloop(const short* __restrict__ wp, int nch,
                                      const short* Hh, int nt0, int quad, int l16,
                                      f32x4 (&acc)[MT][NTC]) {
#pragma unroll
    for (int mt = 0; mt < MT; ++mt)
#pragma unroll
        for (int i = 0; i < NTC; ++i)
#pragma unroll
            for (int r = 0; r < 4; ++r) acc[mt][i][r] = 0.0f;
#pragma unroll 1
    for (int c = 0; c < nch; ++c) {
        const short* cb = wp + (size_t)(c * 19 + nt0) * 1024 + quad * 128 + l16 * 8;
        short8 ah[MT];
#pragma unroll
        for (int mt = 0; mt < MT; ++mt)
            ah[mt] = *(const short8*)&Hh[(mt * 16 + l16) * KS + c * 32 + quad * 8];
        short8 bb[NTC];
#pragma unroll
        for (int i = 0; i < NTC; ++i) bb[i] = *(const short8*)(cb + (size_t)i * 1024);
#pragma unroll
        for (int mt = 0; mt < MT; ++mt)
#pragma unroll
            for (int i = 0; i < NTC; ++i)
                acc[mt][i] = MFMA_B16(ah[mt], bb[i], acc[mt][i]);
#pragma unroll
        for (int i = 0; i < NTC; ++i) bb[i] = *(const short8*)(cb + (size_t)i * 1024 + 512);
#pragma unroll
        for (int mt = 0; mt < MT; ++mt)
#pragma unroll
            for (int i = 0; i < NTC; ++i)
                acc[mt][i] = MFMA_B16(ah[mt], bb[i], acc[mt][i]);
    }
}

// Software-pipelined kloop (k_fuse ONLY, MT=1: ~50 spare VGPRs; R5-verified
// worth ~-12us on the residue).
template <int MT, int NTC>
__device__ __forceinline__ void kloop_p(const short* __restrict__ wp, int nch,
                                        const short* Hh, int nt0, int quad, int l16,
                                        f32x4 (&acc)[MT][NTC]) {
#pragma unroll
    for (int mt = 0; mt < MT; ++mt)
#pragma unroll
        for (int i = 0; i < NTC; ++i)
#pragma unroll
            for (int r = 0; r < 4; ++r) acc[mt][i][r] = 0.0f;

    const short* a0 = Hh + l16 * KS + quad * 8;
    const short* w0 = wp + (size_t)nt0 * 1024 + (size_t)(quad * 128 + l16 * 8);

    short8 ah[MT], an[MT], b1[NTC], b1n[NTC], b2[NTC];
#pragma unroll
    for (int mt = 0; mt < MT; ++mt) ah[mt] = *(const short8*)(a0 + mt * 16 * KS);
#pragma unroll
    for (int i = 0; i < NTC; ++i) b1[i] = *(const short8*)(w0 + (size_t)i * 1024);

#pragma unroll 1
    for (int c = 0; c < nch - 1; ++c) {
        const short* wc = w0 + (size_t)c * 19456;
        const short* wn = wc + 19456;
        const short* apn = a0 + (c + 1) * 32;
#pragma unroll
        for (int i = 0; i < NTC; ++i) b2[i] = *(const short8*)(wc + (size_t)i * 1024 + 512);
#pragma unroll
        for (int mt = 0; mt < MT; ++mt) an[mt] = *(const short8*)(apn + mt * 16 * KS);
#pragma unroll
        for (int i = 0; i < NTC; ++i) b1n[i] = *(const short8*)(wn + (size_t)i * 1024);
#pragma unroll
        for (int mt = 0; mt < MT; ++mt)
#pragma unroll
            for (int i = 0; i < NTC; ++i) acc[mt][i] = MFMA_B16(ah[mt], b1[i], acc[mt][i]);
#pragma unroll
        for (int mt = 0; mt < MT; ++mt)
#pragma unroll
            for (int i = 0; i < NTC; ++i) acc[mt][i] = MFMA_B16(ah[mt], b2[i], acc[mt][i]);
#pragma unroll
        for (int mt = 0; mt < MT; ++mt) ah[mt] = an[mt];
#pragma unroll
        for (int i = 0; i < NTC; ++i) b1[i] = b1n[i];
    }
    {
        const short* wc = w0 + (size_t)(nch - 1) * 19456;
#pragma unroll
        for (int i = 0; i < NTC; ++i) b2[i] = *(const short8*)(wc + (size_t)i * 1024 + 512);
#pragma unroll
        for (int mt = 0; mt < MT; ++mt)
#pragma unroll
            for (int i = 0; i < NTC; ++i) acc[mt][i] = MFMA_B16(ah[mt], b1[i], acc[mt][i]);
#pragma unroll
        for (int mt = 0; mt < MT; ++mt)
#pragma unroll
            for (int i = 0; i < NTC; ++i) acc[mt][i] = MFMA_B16(ah[mt], b2[i], acc[mt][i]);
    }
}

template <int MT, int NTC>
__device__ __forceinline__ void gcn_epilogue(const float* __restrict__ bias,
                                             int nt0, int quad, int l16,
                                             f32x4 (&acc)[MT][NTC], short* Hh) {
#pragma unroll
    for (int i = 0; i < NTC; ++i) {
        int c = (nt0 + i) * 16 + l16;
        float b = (c < HID) ? bias[c] : 0.0f;
#pragma unroll
        for (int mt = 0; mt < MT; ++mt)
#pragma unroll
            for (int r = 0; r < 4; ++r) {
                float v = fmaxf(acc[mt][i][r] + b, 0.0f);
                Hh[(mt * 16 + quad * 4 + r) * KS + c] = bf16r(v);
            }
    }
}

template <int MT, int NTC>
__device__ __forceinline__ void gcn_final(const float* __restrict__ bias,
                                          int nt0, int quad, int l16,
                                          f32x4 (&acc)[MT][NTC],
                                          float* __restrict__ gout) {
#pragma unroll
    for (int i = 0; i < NTC; ++i) {
        int c = (nt0 + i) * 16 + l16;
        float b = (c < HID) ? bias[c] : 0.0f;
        float s = 0.0f;
#pragma unroll
        for (int mt = 0; mt < MT; ++mt)
#pragma unroll
            for (int r = 0; r < 4; ++r) s += fmaxf(acc[mt][i][r] + b, 0.0f);
        s += __shfl_xor(s, 16, 64);
        s += __shfl_xor(s, 32, 64);
        if (quad == 0) gout[c] = (c < HID) ? s : 0.0f;
    }
}

template <int MT, int NTC>
__device__ __forceinline__ void gemm_out(int base, int nt0, int quad, int l16,
                                         f32x4 (&acc)[MT][NTC],
                                         unsigned short* __restrict__ HW) {
#pragma unroll
    for (int i = 0; i < NTC; ++i) {
        int c = (nt0 + i) * 16 + l16;
#pragma unroll
        for (int mt = 0; mt < MT; ++mt)
#pragma unroll
            for (int r = 0; r < 4; ++r) {
                int gm = base + mt * 16 + quad * 4 + r;
                if (gm < N_NODES)
                    HW[(size_t)gm * HIDP + c] = (unsigned short)bf16r(acc[mt][i][r]);
            }
    }
}

// ---------------------------------------------------------------------------
// k_mega: partB (1875, 80 rows, 5 M-tiles) U gemmA-L0 (125) U CSR-fill (313).
// EXACT R0 config: (512,4) = 128-reg budget (124 used), 2 blocks/CU.
// Verified 198-207 us / MfmaUtil 54-56 five times. R6 lesson: do NOT
// co-schedule partB with the gather — L2 pollution re-prices the gather.
// ---------------------------------------------------------------------------
__global__ __launch_bounds__(512, 4) void k_mega(
    const float* __restrict__ edge_attr,
    const float* __restrict__ edge_w,
    const float* __restrict__ edge_b,
    const short* __restrict__ wt0,
    const short* __restrict__ wtl,
    const float* __restrict__ gcn0_b,
    const float* __restrict__ gcn_b,
    float* __restrict__ gpartB,      // [PARTB_BLOCKS][HIDP] plain partials
    unsigned short* __restrict__ hw0,
    const int* __restrict__ row,
    const int* __restrict__ col,
    int* __restrict__ cursor,
    const float* __restrict__ dinv,
    int2* __restrict__ edge_pack) {
    __shared__ short Hh[RBM * KS];   // 52480 B
    int bid = blockIdx.x, t = threadIdx.x;
    int lane = t & 63, w = t >> 6;
    int l16 = lane & 15, quad = lane >> 4;
    int nt0 = (w < 3) ? w * 3 : 9 + (w - 3) * 2;

    if (bid < PARTB_BLOCKS) {
        // ---------------- Part B unit (fused 5-layer), exact 80 rows -------
        int base = N_NODES + bid * RBM;
        for (int i = t; i < RBM * 8; i += 512) {
            int r = i >> 3, c4 = (i & 7) * 4;
            const float* ar = edge_attr + (size_t)(base + r) * 3;
            float a0 = ar[0], a1 = ar[1], a2 = ar[2];
#pragma unroll
            for (int j = 0; j < 4; ++j) {
                int cc = c4 + j;
                float v = edge_b[cc];
                v = fmaf(a0, edge_w[cc], v);
                v = fmaf(a1, edge_w[32 + cc], v);
                v = fmaf(a2, edge_w[64 + cc], v);
                Hh[r * KS + cc] = bf16r(v);
            }
        }
        for (int i = t; i < RBM * 24; i += 512) {
            int r = i / 24, k = 304 + i % 24;
            Hh[r * KS + k] = 0;
        }
        __syncthreads();

        float* gout = gpartB + (size_t)bid * HIDP;
        if (w < 3) {
            f32x4 acc[5][3];
            kloop<5, 3>(wt0, 1, Hh, nt0, quad, l16, acc);
            __syncthreads();
            gcn_epilogue<5, 3>(gcn0_b, nt0, quad, l16, acc, Hh);
            __syncthreads();
            for (int l = 0; l < 4; ++l) {
                kloop<5, 3>(wtl + (size_t)l * 194560, 10, Hh, nt0, quad, l16, acc);
                __syncthreads();
                if (l < 3) {
                    gcn_epilogue<5, 3>(gcn_b + l * HID, nt0, quad, l16, acc, Hh);
                    __syncthreads();
                } else {
                    gcn_final<5, 3>(gcn_b + l * HID, nt0, quad, l16, acc, gout);
                }
            }
        } else {
            f32x4 acc[5][2];
            kloop<5, 2>(wt0, 1, Hh, nt0, quad, l16, acc);
            __syncthreads();
            gcn_epilogue<5, 2>(gcn0_b, nt0, quad, l16, acc, Hh);
            __syncthreads();
            for (int l = 0; l < 4; ++l) {
                kloop<5, 2>(wtl + (size_t)l * 194560, 10, Hh, nt0, quad, l16, acc);
                __syncthreads();
                if (l < 3) {
                    gcn_epilogue<5, 2>(gcn_b + l * HID, nt0, quad, l16, acc, Hh);
                    __syncthreads();
                } else {
                    gcn_final<5, 2>(gcn_b + l * HID, nt0, quad, l16, acc, gout);
                }
            }
        }
    } else if (bid < PARTB_BLOCKS + GEMMA_BLOCKS) {
        // ---------------- Part A layer-0 GEMM (exact 125 x 80 rows) --------
        int base = (bid - PARTB_BLOCKS) * RBM;
        for (int i = t; i < RBM * 8; i += 512) {
            int r = i >> 3, c4 = (i & 7) * 4;
            const float* ar = edge_attr + (size_t)(base + r) * 3;
            float a0 = ar[0], a1 = ar[1], a2 = ar[2];
#pragma unroll
            for (int j = 0; j < 4; ++j) {
                int cc = c4 + j;
                float v = edge_b[cc];
                v = fmaf(a0, edge_w[cc], v);
                v = fmaf(a1, edge_w[32 + cc], v);
                v = fmaf(a2, edge_w[64 + cc], v);
                Hh[r * KS + cc] = bf16r(v);
            }
        }
        for (int i = t; i < RBM * 24; i += 512) {
            int r = i / 24, k = 304 + i % 24;
            Hh[r * KS + k] = 0;
        }
        __syncthreads();
        if (w < 3) {
            f32x4 acc[5][3];
            kloop<5, 3>(wt0, 1, Hh, nt0, quad, l16, acc);
            gemm_out<5, 3>(base, nt0, quad, l16, acc, hw0);
        } else {
            f32x4 acc[5][2];
            kloop<5, 2>(wt0, 1, Hh, nt0, quad, l16, acc);
            gemm_out<5, 2>(base, nt0, quad, l16, acc, hw0);
        }
    } else {
        // ---------------- CSR fill (row, norm) ----------------
        int e = (bid - PARTB_BLOCKS - GEMMA_BLOCKS) * 512 + t;
        if (e < N_EDGES) {
            int c = col[e], r = row[e];
            int p = atomicAdd(&cursor[c], 1);
            edge_pack[p] = make_int2(r, __float_as_int(dinv[r] * dinv[c]));
        }
    }
}

// ---------------------------------------------------------------------------
// agg primitives (scalar u16 gather — R3 lesson: cache-line requests are the
// cost unit; 5 u16 loads/edge = 10 lines, do NOT widen).
// ---------------------------------------------------------------------------
__device__ __forceinline__ void agg_edge4(int i, int lane,
                                          const unsigned short* __restrict__ hw_in,
                                          const int2* __restrict__ ep,
                                          float (&v)[5]) {
    int2 e0 = ep[i], e1 = ep[i + 1], e2 = ep[i + 2], e3 = ep[i + 3];
    const unsigned short* h0 = hw_in + (size_t)e0.x * HIDP;
    const unsigned short* h1 = hw_in + (size_t)e1.x * HIDP;
    const unsigned short* h2 = hw_in + (size_t)e2.x * HIDP;
    const unsigned short* h3 = hw_in + (size_t)e3.x * HIDP;
    float n0 = __int_as_float(e0.y), n1 = __int_as_float(e1.y);
    float n2 = __int_as_float(e2.y), n3 = __int_as_float(e3.y);
#pragma unroll
    for (int jj = 0; jj < 5; ++jj) {
        int cc = lane + 64 * jj;
        if (cc < HIDP) {
            float s = v[jj];
            s = fmaf(n0, b2f(h0[cc]), s);
            s = fmaf(n1, b2f(h1[cc]), s);
            s = fmaf(n2, b2f(h2[cc]), s);
            s = fmaf(n3, b2f(h3[cc]), s);
            v[jj] = s;
        }
    }
}

// Two-row interleaved gather (R5-verified neutral-to-slightly-positive; kept).
__device__ __forceinline__ void agg_pair(int c0, int c1, int lane,
                                         const unsigned short* __restrict__ hw_in,
                                         const int* __restrict__ col_start,
                                         const int2* __restrict__ ep,
                                         float (&v0)[5], float (&v1)[5]) {
#pragma unroll
    for (int jj = 0; jj < 5; ++jj) { v0[jj] = 0.0f; v1[jj] = 0.0f; }
    int i0 = col_start[c0], e0 = col_start[c0 + 1];
    int i1 = col_start[c1], e1 = col_start[c1 + 1];
#pragma unroll 1
    while (i0 + 4 <= e0 && i1 + 4 <= e1) {
        int2 a0 = ep[i0], a1 = ep[i0 + 1], a2 = ep[i0 + 2], a3 = ep[i0 + 3];
        int2 b0 = ep[i1], b1 = ep[i1 + 1], b2 = ep[i1 + 2], b3 = ep[i1 + 3];
        const unsigned short* pa0 = hw_in + (size_t)a0.x * HIDP;
        const unsigned short* pa1 = hw_in + (size_t)a1.x * HIDP;
        const unsigned short* pa2 = hw_in + (size_t)a2.x * HIDP;
        const unsigned short* pa3 = hw_in + (size_t)a3.x * HIDP;
        const unsigned short* pb0 = hw_in + (size_t)b0.x * HIDP;
        const unsigned short* pb1 = hw_in + (size_t)b1.x * HIDP;
        const unsigned short* pb2 = hw_in + (size_t)b2.x * HIDP;
        const unsigned short* pb3 = hw_in + (size_t)b3.x * HIDP;
        float na0 = __int_as_float(a0.y), na1 = __int_as_float(a1.y);
        float na2 = __int_as_float(a2.y), na3 = __int_as_float(a3.y);
        float nb0 = __int_as_float(b0.y), nb1 = __int_as_float(b1.y);
        float nb2 = __int_as_float(b2.y), nb3 = __int_as_float(b3.y);
#pragma unroll
        for (int jj = 0; jj < 5; ++jj) {
            int cc = lane + 64 * jj;
            if (cc < HIDP) {
                float s = v0[jj];
                s = fmaf(na0, b2f(pa0[cc]), s);
                s = fmaf(na1, b2f(pa1[cc]), s);
                s = fmaf(na2, b2f(pa2[cc]), s);
                s = fmaf(na3, b2f(pa3[cc]), s);
                v0[jj] = s;
                float u = v1[jj];
                u = fmaf(nb0, b2f(pb0[cc]), u);
                u = fmaf(nb1, b2f(pb1[cc]), u);
                u = fmaf(nb2, b2f(pb2[cc]), u);
                u = fmaf(nb3, b2f(pb3[cc]), u);
                v1[jj] = u;
            }
        }
        i0 += 4; i1 += 4;
    }
#pragma unroll 1
    for (; i0 + 4 <= e0; i0 += 4) agg_edge4(i0, lane, hw_in, ep, v0);
#pragma unroll 1
    for (; i0 < e0; ++i0) {
        int2 q = ep[i0];
        const unsigned short* h = hw_in + (size_t)q.x * HIDP;
        float n = __int_as_float(q.y);
#pragma unroll
        for (int jj = 0; jj < 5; ++jj) {
            int cc = lane + 64 * jj;
            if (cc < HIDP) v0[jj] = fmaf(n, b2f(h[cc]), v0[jj]);
        }
    }
#pragma unroll 1
    for (; i1 + 4 <= e1; i1 += 4) agg_edge4(i1, lane, hw_in, ep, v1);
#pragma unroll 1
    for (; i1 < e1; ++i1) {
        int2 q = ep[i1];
        const unsigned short* h = hw_in + (size_t)q.x * HIDP;
        float n = __int_as_float(q.y);
#pragma unroll
        for (int jj = 0; jj < 5; ++jj) {
            int cc = lane + 64 * jj;
            if (cc < HIDP) v1[jj] = fmaf(n, b2f(h[cc]), v1[jj]);
        }
    }
}

// ---------------------------------------------------------------------------
// k_fuse: pair-agg(prev hw) -> relu+bias -> LDS -> piped gemm -> next hw.
// RBF=16 -> 625 blocks; wave's 2 rows gathered concurrently; kloop_p (MT=1).
// R5-verified.
// ---------------------------------------------------------------------------
__global__ __launch_bounds__(512, 4) void k_fuse(
    const unsigned short* __restrict__ hw_in,
    const int* __restrict__ col_start,
    const int2* __restrict__ edge_pack,
    const float* __restrict__ selfnorm,
    const float* __restrict__ bias,
    const short* __restrict__ wt,
    unsigned short* __restrict__ hw_out) {
    __shared__ short Hh[RBF * KS];   // 10496 B
    int t = threadIdx.x;
    int lane = t & 63, w = t >> 6;
    int l16 = lane & 15, quad = lane >> 4;
    int base = blockIdx.x * RBF;
    int nt0 = (w < 3) ? w * 3 : 9 + (w - 3) * 2;

    {
        int c0 = base + w * 2, c1 = c0 + 1;   // 625*16 == 10000: always valid
        float v0[5], v1[5];
        agg_pair(c0, c1, lane, hw_in, col_start, edge_pack, v0, v1);
        float sn0 = selfnorm[c0], sn1 = selfnorm[c1];
        const unsigned short* sp0 = hw_in + (size_t)c0 * HIDP;
        const unsigned short* sp1 = hw_in + (size_t)c1 * HIDP;
        int r0 = w * 2;
#pragma unroll
        for (int jj = 0; jj < 5; ++jj) {
            int cc = lane + 64 * jj;
            if (cc < HIDP) {
                float b = (cc < HID) ? bias[cc] : 0.0f;
                float h0 = v0[jj] + sn0 * b2f(sp0[cc]) + b;
                float h1 = v1[jj] + sn1 * b2f(sp1[cc]) + b;
                Hh[r0 * KS + cc] = bf16r(fmaxf(h0, 0.0f));
                Hh[(r0 + 1) * KS + cc] = bf16r(fmaxf(h1, 0.0f));
            }
        }
    }
    for (int i = t; i < RBF * 6; i += 512) {
        int r = i / 6, k = 304 + (i % 6) * 4;
        *(s16x4*)&Hh[r * KS + k] = (s16x4)0;
    }
    __syncthreads();

    if (w < 3) {
        f32x4 acc[1][3];
        kloop_p<1, 3>(wt, 10, Hh, nt0, quad, l16, acc);
        gemm_out<1, 3>(base, nt0, quad, l16, acc, hw_out);
    } else {
        f32x4 acc[1][2];
        kloop_p<1, 2>(wt, 10, Hh, nt0, quad, l16, acc);
        gemm_out<1, 2>(base, nt0, quad, l16, acc, hw_out);
    }
}

// ---------------------------------------------------------------------------
// k_last: final Part-A pair-agg + colsum into g_sum, with gpartB fold
// absorbed (waves 0..2 each add one gpartB row; 625*3 == 1875 exact).
// ---------------------------------------------------------------------------
__global__ __launch_bounds__(512) void k_last(
    const unsigned short* __restrict__ hw_in,
    const int* __restrict__ col_start,
    const int2* __restrict__ edge_pack,
    const float* __restrict__ selfnorm,
    const float* __restrict__ bias,
    const float* __restrict__ gpartB,
    float* __restrict__ g_sum) {
    __shared__ float red[8 * 320];
    int t = threadIdx.x;
    int lane = t & 63, w = t >> 6;
    int base = blockIdx.x * RBF;

    float s[5] = {0.0f, 0.0f, 0.0f, 0.0f, 0.0f};
    {
        int c0 = base + w * 2, c1 = c0 + 1;    // always valid
        float v0[5], v1[5];
        agg_pair(c0, c1, lane, hw_in, col_start, edge_pack, v0, v1);
        float sn0 = selfnorm[c0], sn1 = selfnorm[c1];
        const unsigned short* sp0 = hw_in + (size_t)c0 * HIDP;
        const unsigned short* sp1 = hw_in + (size_t)c1 * HIDP;
#pragma unroll
        for (int jj = 0; jj < 5; ++jj) {
            int cc = lane + 64 * jj;
            if (cc < HID) {
                float b = bias[cc];
                s[jj] += fmaxf(v0[jj] + sn0 * b2f(sp0[cc]) + b, 0.0f);
                s[jj] += fmaxf(v1[jj] + sn1 * b2f(sp1[cc]) + b, 0.0f);
            }
        }
    }
    if (w < 3) {
        int rr = blockIdx.x * 3 + w;
        if (rr < PARTB_BLOCKS) {
#pragma unroll
            for (int jj = 0; jj < 5; ++jj) {
                int cc = lane + 64 * jj;
                if (cc < HID) s[jj] += gpartB[(size_t)rr * HIDP + cc];
            }
        }
    }
#pragma unroll
    for (int jj = 0; jj < 5; ++jj) red[w * 320 + lane + 64 * jj] = s[jj];
    __syncthreads();
    if (w == 0) {
#pragma unroll
        for (int jj = 0; jj < 5; ++jj) {
            int cc = lane + 64 * jj;
            if (cc < HID) {
                float tot = 0.0f;
#pragma unroll
                for (int g = 0; g < 8; ++g) tot += red[g * 320 + cc];
                atomicAdd(&g_sum[cc], tot);
            }
        }
    }
}

__global__ void k_head(const float* __restrict__ g_sum,
                       const float* __restrict__ lin1_w, const float* __restrict__ lin1_b,
                       const float* __restrict__ lin2_w, const float* __restrict__ lin2_b,
                       float* __restrict__ out) {
    __shared__ float g2[32];
    int t = threadIdx.x;
    const float inv = 1.0f / (float)N_EDGES;
    if (t < 32) {
        float a = lin1_b[t];
        for (int d = 0; d < HID; ++d) a = fmaf(g_sum[d] * inv, lin1_w[d * 32 + t], a);
        g2[t] = fmaxf(a, 0.0f);
    }
    __syncthreads();
    if (t < 2) {
        float p = lin2_b[t];
        for (int j = 0; j < 32; ++j) p = fmaf(g2[j], lin2_w[j * 2 + t], p);
        out[t] = p;
    }
}

// ---------------------------------------------------------------------------

extern "C" void kernel_launch(void* const* d_in, const int* in_sizes, int n_in,
                              void* d_out, int out_size, void* d_ws, size_t ws_size,
                              hipStream_t stream) {
    (void)in_sizes; (void)n_in; (void)out_size; (void)ws_size;
    const int* edge_index = (const int*)d_in[1];
    const float* edge_attr = (const float*)d_in[2];
    const float* edge_w = (const float*)d_in[6];
    const float* edge_b = (const float*)d_in[7];
    const float* gcn0_w = (const float*)d_in[8];
    const float* gcn0_b = (const float*)d_in[9];
    const float* gcn_w = (const float*)d_in[10];
    const float* gcn_b = (const float*)d_in[11];
    const float* lin1_w = (const float*)d_in[12];
    const float* lin1_b = (const float*)d_in[13];
    const float* lin2_w = (const float*)d_in[14];
    const float* lin2_b = (const float*)d_in[15];

    char* ws = (char*)d_ws;
    size_t off = 0;
    auto alloc = [&](size_t bytes) {
        void* p = ws + off;
        off = (off + bytes + 255) & ~(size_t)255;
        return p;
    };
    unsigned short* hwA = (unsigned short*)alloc((size_t)N_NODES * HIDP * 2);
    unsigned short* hwB = (unsigned short*)alloc((size_t)N_NODES * HIDP * 2);
    int2* edge_pack = (int2*)alloc((size_t)N_EDGES * 8);
    int* cnt = (int*)alloc((size_t)N_NODES * 4);
    int* col_start = (int*)alloc((size_t)(N_NODES + 1) * 4);
    int* cursor = (int*)alloc((size_t)N_NODES * 4);
    float* dinv = (float*)alloc((size_t)N_NODES * 4);
    float* selfnorm = (float*)alloc((size_t)N_NODES * 4);
    float* g_sum = (float*)alloc((size_t)HIDP * 4);
    short* wt0 = (short*)alloc((size_t)38912);
    short* wtl = (short*)alloc((size_t)4 * 389120);
    float* gpartB = (float*)alloc((size_t)PARTB_BLOCKS * HIDP * 4);

    const int* row = edge_index;
    const int* col = edge_index + N_EDGES;

    hipMemsetAsync(cnt, 0, N_NODES * 4, stream);
    hipMemsetAsync(g_sum, 0, HIDP * 4, stream);

    k_prep<<<(N_EDGES + 255) / 256, 256, 0, stream>>>(gcn0_w, gcn_w, wt0, wtl, col, cnt);
    k_scan<<<1, 1024, 0, stream>>>(cnt, col_start, cursor, dinv, selfnorm);

    // mega: partB (heavy, first) + Part-A L0 + CSR fill (cheap tail pad)
    k_mega<<<MEGA_BLOCKS, 512, 0, stream>>>(edge_attr, edge_w, edge_b, wt0, wtl,
                                            gcn0_b, gcn_b, gpartB, hwA,
                                            row, col, cursor, dinv, edge_pack);

    // Part A layers 1..4: fused agg+gemm per layer (625 blocks each)
    k_fuse<<<FUSE_BLOCKS, 512, 0, stream>>>(hwA, col_start, edge_pack, selfnorm,
                                            gcn0_b, wtl + (size_t)0 * 194560, hwB);
    k_fuse<<<FUSE_BLOCKS, 512, 0, stream>>>(hwB, col_start, edge_pack, selfnorm,
                                            gcn_b + 0 * HID, wtl + (size_t)1 * 194560, hwA);
    k_fuse<<<FUSE_BLOCKS, 512, 0, stream>>>(hwA, col_start, edge_pack, selfnorm,
                                            gcn_b + 1 * HID, wtl + (size_t)2 * 194560, hwB);
    k_fuse<<<FUSE_BLOCKS, 512, 0, stream>>>(hwB, col_start, edge_pack, selfnorm,
                                            gcn_b + 2 * HID, wtl + (size_t)3 * 194560, hwA);
    // final agg + colsum + partB fold, then head
    k_last<<<FUSE_BLOCKS, 512, 0, stream>>>(hwA, col_start, edge_pack, selfnorm,
                                            gcn_b + 3 * HID, gpartB, g_sum);
    k_head<<<1, 64, 0, stream>>>(g_sum, lin1_w, lin1_b, lin2_w, lin2_b, (float*)d_out);
}